// Round 2
// baseline (352.730 us; speedup 1.0000x reference)
//
#include <hip/hip_runtime.h>

// GCN: agg-before-GEMM on both layers (A(hW) = (Ah)W).
//   es  = bf16( dinv[i] * emb[x[i]] )               (N x 32, 3.2 MB, L2-resident)
//   L1 fused: a1(LDS) = dinv*(es[i]+sum es[src]);  hs = bf16(dinv*relu(a1@W1+b1))
//   L2 fused: a2 = dinv*(hs[i]+sum hs[src]);  out = a2@W2 + b2
// CSR build: bucket -> chunked-LDS-histogram counting sort (no global atomics),
// staged edges packed to one int ((dlocal<<17)|src) - halves staging traffic.
// R12: k_l2 was L3-latency-bound (FETCH 151MB @ 1.8TB/s, VALUBusy 36%): hs
// (12.8MB) >> 4MB per-XCD L2 with uniform-random gather. New k_part 4-way
// partitions each CSR row by src-chunk (12500 nodes = 3.2MB hs per chunk);
// k_l2 rebuilt chunk-major with register accumulators and a fully-resident
// grid (1250 blocks x 40 nodes, launch_bounds(256,5)) so all blocks sweep
// the same src chunk concurrently -> gather becomes L2-resident. csr stream
// reads are nontemporal so they don't evict the hs chunk.
// R13: fix compile - __builtin_nontemporal_store needs a native clang vector
// type, not HIP's float4 class; store via ext_vector_type(4) alias.

#define NPP   6250     // nodes per partition (N=50000 / 8)
#define NC    32       // chunks per partition
#define CAP   96       // max row length handled by k_part (P(deg>96) ~ 0)
#define CAPP  97       // padded LDS stride (97 % 32 != 0 -> no bank aliasing)
#define NPB   40       // nodes per k_l2 block (1250 blocks, all co-resident)

typedef float vfloat4 __attribute__((ext_vector_type(4)));

static inline int cdiv(int a, int b){ return (a + b - 1) / b; }

__device__ __forceinline__ unsigned short f2bf(float f){
    unsigned int u = __float_as_uint(f);
    u += 0x7fffu + ((u >> 16) & 1u);          // round-to-nearest-even
    return (unsigned short)(u >> 16);
}
__device__ __forceinline__ float bf2f(unsigned short b){
    return __uint_as_float(((unsigned int)b) << 16);
}

__device__ __forceinline__ void nt_store4(float* p, const float4& v){
    vfloat4 t = {v.x, v.y, v.z, v.w};
    __builtin_nontemporal_store(t, (vfloat4*)p);
}

__global__ void k_zero_i32(int* __restrict__ p, int n){
    int i = blockIdx.x * blockDim.x + threadIdx.x;
    if (i < n) p[i] = 0;
}

// Bucket edges by dst-range into 8 staged partition arrays, packed
// (dlocal<<17)|src. LDS tiles, per-block coalesced flush (~2k gcur atomics total).
__global__ __launch_bounds__(256) void k_bucket(const int* __restrict__ src,
        const int* __restrict__ dst, int E, int* __restrict__ staged,
        int* __restrict__ gcur, int npp, int C){
    __shared__ int qcnt[8];
    __shared__ int qbase[8];
    __shared__ int qbuf[8 * 256];   // 8 KB
    int tid = threadIdx.x;
    if (tid < 8) qcnt[tid] = 0;
    __syncthreads();
    int e0 = blockIdx.x * 1024 + tid * 4;
    if (e0 + 3 < E){
        int4 d4 = *(const int4*)(dst + e0);
        int4 s4 = *(const int4*)(src + e0);
        int dd[4] = {d4.x, d4.y, d4.z, d4.w};
        int ss[4] = {s4.x, s4.y, s4.z, s4.w};
        #pragma unroll
        for (int i = 0; i < 4; i++){
            int p = dd[i] / npp;
            int pk = ((dd[i] - p * npp) << 17) | ss[i];
            int pos = atomicAdd(&qcnt[p], 1);
            if (pos < 256) qbuf[p * 256 + pos] = pk;
            else {          // statistically unreachable overflow fallback
                int gp = atomicAdd(&gcur[p], 1);
                staged[(size_t)p * C + gp] = pk;
            }
        }
    } else {
        for (int e = e0; e < E && e < e0 + 4; e++){
            int d = dst[e], s = src[e];
            int p = d / npp;
            int pk = ((d - p * npp) << 17) | s;
            int pos = atomicAdd(&qcnt[p], 1);
            if (pos < 256) qbuf[p * 256 + pos] = pk;
            else {
                int gp = atomicAdd(&gcur[p], 1);
                staged[(size_t)p * C + gp] = pk;
            }
        }
    }
    __syncthreads();
    if (tid < 8){
        int nq = min(qcnt[tid], 256);
        qbase[tid] = (nq > 0) ? atomicAdd(&gcur[tid], nq) : 0;
    }
    __syncthreads();
    for (int b = 0; b < 8; b++){
        int nq = min(qcnt[b], 256);
        int gb = qbase[b];
        for (int i = tid; i < nq; i += 256)
            staged[(size_t)b * C + gb + i] = qbuf[b * 256 + i];
    }
}

// Per-(partition,chunk) dst histogram via LDS atomics -> H[p][c][0..npp).
__global__ __launch_bounds__(256) void k_hist(const int* __restrict__ staged,
        const int* __restrict__ gcur, int C, int CH, int npp, int* __restrict__ H){
    __shared__ int hist[NPP];
    int part  = blockIdx.x & 7;
    int chunk = blockIdx.x >> 3;
    int tid = threadIdx.x;
    for (int i = tid; i < npp; i += 256) hist[i] = 0;
    __syncthreads();
    int pc = gcur[part];
    int e0 = chunk * CH, e1 = min(e0 + CH, pc);
    const int* sd = staged + (size_t)part * C;
    for (int e = e0 + tid; e < e1; e += 256)
        atomicAdd(&hist[(unsigned)sd[e] >> 17], 1);
    __syncthreads();
    int* Hrow = H + (size_t)(part * NC + chunk) * npp;
    for (int i = tid; i < npp; i += 256) Hrow[i] = hist[i];
}

// Per-node serial prefix over the NC chunk histograms: H becomes per-chunk
// exclusive base rank; ecount = total; dinv fused; per-block sums -> bsum.
__global__ __launch_bounds__(256) void k_nodescan(int* __restrict__ H, int npp, int n,
        int* __restrict__ ecount, float* __restrict__ dinv, int* __restrict__ bsum){
    __shared__ int s[256];
    int t = blockIdx.x * 256 + threadIdx.x;   // t == node id (partitions contiguous)
    int run = 0;
    if (t < 8 * npp && t < n){
        int p  = t / npp;
        int dl = t - p * npp;
        #pragma unroll
        for (int c = 0; c < NC; c++){
            size_t idx = (size_t)(p * NC + c) * npp + dl;
            int v = H[idx];
            H[idx] = run;
            run += v;
        }
        ecount[t] = run;
        dinv[t] = rsqrtf((float)run + 1.0f);   // +1 self-loop
    }
    s[threadIdx.x] = run;
    __syncthreads();
    for (int d = 128; d > 0; d >>= 1){
        if (threadIdx.x < d) s[threadIdx.x] += s[threadIdx.x + d];
        __syncthreads();
    }
    if (threadIdx.x == 0) bsum[blockIdx.x] = s[0];
}

// Fused scanB+scanC: every block re-scans the nb block sums in LDS (nb<=256),
// then does its 256-element Hillis-Steele scan -> offsets.
__global__ __launch_bounds__(256) void k_scanBC(const int* __restrict__ ecount, int n,
        const int* __restrict__ bsum, int nb, int* __restrict__ offsets){
    __shared__ int bs[256];
    __shared__ int s[256];
    int t = threadIdx.x;
    bs[t] = (t < nb) ? bsum[t] : 0;
    __syncthreads();
    if (t == 0){
        int run = 0;
        for (int b = 0; b < nb; b++){ int v = bs[b]; bs[b] = run; run += v; }
    }
    __syncthreads();
    int i = blockIdx.x * 256 + t;
    int v = (i < n) ? ecount[i] : 0;
    s[t] = v;
    __syncthreads();
    for (int d = 1; d < 256; d <<= 1){
        int x = (t >= d) ? s[t - d] : 0;
        __syncthreads();
        s[t] += x;
        __syncthreads();
    }
    if (i < n) offsets[i] = bs[blockIdx.x] + s[t] - v;
}

// Fill csr via LDS cursor preloaded with chunk base ranks. No global atomics.
__global__ __launch_bounds__(256) void k_fill3(const int* __restrict__ staged,
        const int* __restrict__ gcur, int C, int CH, int npp,
        const int* __restrict__ H, const int* __restrict__ offsets,
        int* __restrict__ csr_src){
    __shared__ int cur[NPP];
    int part  = blockIdx.x & 7;
    int chunk = blockIdx.x >> 3;
    int tid = threadIdx.x;
    const int* Hrow = H + (size_t)(part * NC + chunk) * npp;
    for (int i = tid; i < npp; i += 256) cur[i] = Hrow[i];
    __syncthreads();
    int pc = gcur[part];
    int lo = part * npp;
    int e0 = chunk * CH, e1 = min(e0 + CH, pc);
    const int* sd = staged + (size_t)part * C;
    for (int e = e0 + tid; e < e1; e += 256){
        int pk = sd[e];
        int dl = (unsigned)pk >> 17;
        int r = atomicAdd(&cur[dl], 1);
        csr_src[offsets[lo + dl] + r] = pk & 0x1FFFF;
    }
}

// 4-way partition each CSR row by src chunk (src/12500) and record the chunk
// boundaries bnd4[node] = (b1,b2,b3,cnt). Pure perf transform: rows keep the
// same multiset of sources. Fallback (cnt>CAP, statistically unreachable):
// leave row as-is and use quarter boundaries (still correct, just unaligned).
__global__ __launch_bounds__(128) void k_part(const int* __restrict__ offsets,
        const int* __restrict__ ecount, int* __restrict__ csr,
        int4* __restrict__ bnd4, int n, int th1, int th2, int th3){
    __shared__ int buf[128 * CAPP];   // 49.7 KB
    int t = threadIdx.x;
    int node = blockIdx.x * 128 + t;
    if (node >= n) return;
    int off = offsets[node], cnt = ecount[node];
    int4 b;
    if (cnt <= CAP){
        int* mb = buf + t * CAPP;
        int c0 = 0, c1 = 0, c2 = 0;
        for (int i = 0; i < cnt; i++){
            int v = csr[off + i];
            mb[i] = v;
            c0 += (v < th1);
            c1 += (v >= th1) & (v < th2);
            c2 += (v >= th2) & (v < th3);
        }
        int p1 = c0, p2 = c0 + c1, p3 = c0 + c1 + c2;
        int q0 = 0, q1 = p1, q2 = p2, q3 = p3;
        for (int i = 0; i < cnt; i++){
            int v = mb[i];
            int pos;
            if      (v < th1) pos = q0++;
            else if (v < th2) pos = q1++;
            else if (v < th3) pos = q2++;
            else              pos = q3++;
            csr[off + pos] = v;
        }
        b = make_int4(p1, p2, p3, cnt);
    } else {
        int q = cnt >> 2;
        b = make_int4(q, 2 * q, 3 * q, cnt);
    }
    bnd4[node] = b;
}

// es[i][c] = bf16( emb[x[i]][c] * dinv[i] )
__global__ void k_scale(const float* __restrict__ emb, const int* __restrict__ x,
                        const float* __restrict__ dinv, unsigned short* __restrict__ es, int n){
    int idx = blockIdx.x * blockDim.x + threadIdx.x;
    if (idx >= n * 32) return;
    int i = idx >> 5;
    int c = idx & 31;
    es[idx] = f2bf(emb[(size_t)x[i] * 32 + c] * dinv[i]);
}

// Layer 1 fused (R10 form): gather(32-dim es) -> LDS a1 tile -> GEMM W1 -> hs.
// es is 3.2 MB -> fits any single XCD L2; no chunking needed here.
__global__ __launch_bounds__(256) void k_l1(const unsigned short* __restrict__ es,
        const int* __restrict__ offsets, const int* __restrict__ ecount,
        const int* __restrict__ csr, const float* __restrict__ dinv,
        const float* __restrict__ W1, const float* __restrict__ b1,
        unsigned short* __restrict__ hs, int n){
    __shared__ float w[32 * 128];     // 16 KB
    __shared__ float a1t[8][32];      // 1 KB
    for (int i = threadIdx.x; i < 32 * 128; i += 256) w[i] = W1[i];
    int g    = threadIdx.x >> 5;
    int lane = threadIdx.x & 31;
    int node = blockIdx.x * 8 + g;
    // --- phase A: aggregate into LDS ---
    if (node < n){
        int off = offsets[node], cnt = ecount[node];
        float s0 = bf2f(es[(size_t)node * 32 + lane]);   // self-loop term
        float s1 = 0.f;
        int e = 0;
        for (; e + 8 <= cnt; e += 8){
            int i0 = csr[off + e + 0], i1 = csr[off + e + 1];
            int i2 = csr[off + e + 2], i3 = csr[off + e + 3];
            int i4 = csr[off + e + 4], i5 = csr[off + e + 5];
            int i6 = csr[off + e + 6], i7 = csr[off + e + 7];
            unsigned short v0 = es[(size_t)i0 * 32 + lane];
            unsigned short v1 = es[(size_t)i1 * 32 + lane];
            unsigned short v2 = es[(size_t)i2 * 32 + lane];
            unsigned short v3 = es[(size_t)i3 * 32 + lane];
            unsigned short v4 = es[(size_t)i4 * 32 + lane];
            unsigned short v5 = es[(size_t)i5 * 32 + lane];
            unsigned short v6 = es[(size_t)i6 * 32 + lane];
            unsigned short v7 = es[(size_t)i7 * 32 + lane];
            s0 += bf2f(v0) + bf2f(v2) + bf2f(v4) + bf2f(v6);
            s1 += bf2f(v1) + bf2f(v3) + bf2f(v5) + bf2f(v7);
        }
        for (; e < cnt; e++) s0 += bf2f(es[(size_t)csr[off + e] * 32 + lane]);
        a1t[g][lane] = dinv[node] * (s0 + s1);
    }
    __syncthreads();
    // --- phase B: hs[node] = bf16(dinv * relu(a1 @ W1 + b1)) ---
    if (node >= n) return;
    int c4 = lane * 4;
    float4 acc = *(const float4*)(b1 + c4);
    #pragma unroll
    for (int k4 = 0; k4 < 8; k4++){
        float4 av = *(const float4*)&a1t[g][k4 * 4];
        float4 w0 = *(const float4*)&w[(k4 * 4 + 0) * 128 + c4];
        float4 w1 = *(const float4*)&w[(k4 * 4 + 1) * 128 + c4];
        float4 w2 = *(const float4*)&w[(k4 * 4 + 2) * 128 + c4];
        float4 w3 = *(const float4*)&w[(k4 * 4 + 3) * 128 + c4];
        acc.x += av.x * w0.x + av.y * w1.x + av.z * w2.x + av.w * w3.x;
        acc.y += av.x * w0.y + av.y * w1.y + av.z * w2.y + av.w * w3.y;
        acc.z += av.x * w0.z + av.y * w1.z + av.z * w2.z + av.w * w3.z;
        acc.w += av.x * w0.w + av.y * w1.w + av.z * w2.w + av.w * w3.w;
    }
    float dv = dinv[node];
    ushort4 o;
    o.x = f2bf(dv * fmaxf(acc.x, 0.f));
    o.y = f2bf(dv * fmaxf(acc.y, 0.f));
    o.z = f2bf(dv * fmaxf(acc.z, 0.f));
    o.w = f2bf(dv * fmaxf(acc.w, 0.f));
    *(ushort4*)(hs + (size_t)node * 128 + c4) = o;
}

// Layer 2 fused, chunk-major (R12): 40 nodes/block, 1250 blocks, ALL resident
// (launch_bounds(256,5): VGPR<=102; LDS 20.5KB -> >=5 blk/CU capacity=1280).
// Phase A sweeps the 4 src chunks in order with per-node float4 register
// accumulators; concurrent blocks naturally stay phase-aligned, so each pass's
// gathers hit a 3.2MB L2-resident hs slice. csr reads are nontemporal.
// Phase B: thread = 5 rows x 4 cols, W2 from global (64 KB, L2-resident).
__global__ __launch_bounds__(256, 5) void k_l2(const unsigned short* __restrict__ hs,
        const int* __restrict__ offsets, const int4* __restrict__ bnd4,
        const int* __restrict__ csr, const float* __restrict__ dinv,
        const float* __restrict__ W2, const float* __restrict__ b2,
        float* __restrict__ out, int n){
    __shared__ float a2t[NPB * 128];   // 20.5 KB
    int g    = threadIdx.x >> 5;
    int lane = threadIdx.x & 31;
    int c4g  = lane * 4;
    // --- phase A: chunk-major gather, register accumulators ---
    float4 acc[5];
    #pragma unroll
    for (int j = 0; j < 5; j++){
        int node = blockIdx.x * NPB + g + 8 * j;
        if (node < n){
            ushort4 sv = *(const ushort4*)(hs + (size_t)node * 128 + c4g);
            acc[j].x = bf2f(sv.x); acc[j].y = bf2f(sv.y);
            acc[j].z = bf2f(sv.z); acc[j].w = bf2f(sv.w);
        } else {
            acc[j].x = acc[j].y = acc[j].z = acc[j].w = 0.f;
        }
    }
    #pragma unroll
    for (int c = 0; c < 4; c++){
        #pragma unroll
        for (int j = 0; j < 5; j++){
            int node = blockIdx.x * NPB + g + 8 * j;
            if (node >= n) continue;
            int off = offsets[node];
            int4 b = bnd4[node];
            int e0 = (c == 0) ? 0   : (c == 1) ? b.x : (c == 2) ? b.y : b.z;
            int e1 = (c == 0) ? b.x : (c == 1) ? b.y : (c == 2) ? b.z : b.w;
            int e = e0;
            for (; e + 8 <= e1; e += 8){
                int i0 = __builtin_nontemporal_load(csr + off + e + 0);
                int i1 = __builtin_nontemporal_load(csr + off + e + 1);
                int i2 = __builtin_nontemporal_load(csr + off + e + 2);
                int i3 = __builtin_nontemporal_load(csr + off + e + 3);
                int i4 = __builtin_nontemporal_load(csr + off + e + 4);
                int i5 = __builtin_nontemporal_load(csr + off + e + 5);
                int i6 = __builtin_nontemporal_load(csr + off + e + 6);
                int i7 = __builtin_nontemporal_load(csr + off + e + 7);
                ushort4 v0 = *(const ushort4*)(hs + (size_t)i0 * 128 + c4g);
                ushort4 v1 = *(const ushort4*)(hs + (size_t)i1 * 128 + c4g);
                ushort4 v2 = *(const ushort4*)(hs + (size_t)i2 * 128 + c4g);
                ushort4 v3 = *(const ushort4*)(hs + (size_t)i3 * 128 + c4g);
                ushort4 v4 = *(const ushort4*)(hs + (size_t)i4 * 128 + c4g);
                ushort4 v5 = *(const ushort4*)(hs + (size_t)i5 * 128 + c4g);
                ushort4 v6 = *(const ushort4*)(hs + (size_t)i6 * 128 + c4g);
                ushort4 v7 = *(const ushort4*)(hs + (size_t)i7 * 128 + c4g);
                acc[j].x += bf2f(v0.x) + bf2f(v1.x) + bf2f(v2.x) + bf2f(v3.x)
                          + bf2f(v4.x) + bf2f(v5.x) + bf2f(v6.x) + bf2f(v7.x);
                acc[j].y += bf2f(v0.y) + bf2f(v1.y) + bf2f(v2.y) + bf2f(v3.y)
                          + bf2f(v4.y) + bf2f(v5.y) + bf2f(v6.y) + bf2f(v7.y);
                acc[j].z += bf2f(v0.z) + bf2f(v1.z) + bf2f(v2.z) + bf2f(v3.z)
                          + bf2f(v4.z) + bf2f(v5.z) + bf2f(v6.z) + bf2f(v7.z);
                acc[j].w += bf2f(v0.w) + bf2f(v1.w) + bf2f(v2.w) + bf2f(v3.w)
                          + bf2f(v4.w) + bf2f(v5.w) + bf2f(v6.w) + bf2f(v7.w);
            }
            if (e < e1){   // masked batch tail: clamped idx keeps loads in flight
                #pragma unroll
                for (int i = 0; i < 8; i++){
                    int ei = min(e + i, e1 - 1);
                    int idx = __builtin_nontemporal_load(csr + off + ei);
                    ushort4 v = *(const ushort4*)(hs + (size_t)idx * 128 + c4g);
                    if (e + i < e1){
                        acc[j].x += bf2f(v.x); acc[j].y += bf2f(v.y);
                        acc[j].z += bf2f(v.z); acc[j].w += bf2f(v.w);
                    }
                }
            }
        }
    }
    #pragma unroll
    for (int j = 0; j < 5; j++){
        int node = blockIdx.x * NPB + g + 8 * j;
        if (node < n){
            float dv = dinv[node];
            float4 r;
            r.x = dv * acc[j].x; r.y = dv * acc[j].y;
            r.z = dv * acc[j].z; r.w = dv * acc[j].w;
            *(float4*)&a2t[(g + 8 * j) * 128 + c4g] = r;
        }
    }
    __syncthreads();
    // --- phase B: out[rows] = a2t[rows] @ W2 + b2 ; 5 rows x 4 cols/thread ---
    int c4 = lane * 4;                 // output col base
    int r0 = g * 5;                    // 5 local rows
    float4 bias = *(const float4*)(b2 + c4);
    float4 o0 = bias, o1 = bias, o2 = bias, o3 = bias, o4 = bias;
    for (int k = 0; k < 128; k += 4){
        float4 a0 = *(const float4*)&a2t[(r0 + 0) * 128 + k];
        float4 a1v= *(const float4*)&a2t[(r0 + 1) * 128 + k];
        float4 a2v= *(const float4*)&a2t[(r0 + 2) * 128 + k];
        float4 a3v= *(const float4*)&a2t[(r0 + 3) * 128 + k];
        float4 a4v= *(const float4*)&a2t[(r0 + 4) * 128 + k];
        #pragma unroll
        for (int kk = 0; kk < 4; kk++){
            float4 wv = *(const float4*)(W2 + (size_t)(k + kk) * 128 + c4);
            float b0 = (kk == 0) ? a0.x  : (kk == 1) ? a0.y  : (kk == 2) ? a0.z  : a0.w;
            float b1v= (kk == 0) ? a1v.x : (kk == 1) ? a1v.y : (kk == 2) ? a1v.z : a1v.w;
            float b2v= (kk == 0) ? a2v.x : (kk == 1) ? a2v.y : (kk == 2) ? a2v.z : a2v.w;
            float b3 = (kk == 0) ? a3v.x : (kk == 1) ? a3v.y : (kk == 2) ? a3v.z : a3v.w;
            float b4 = (kk == 0) ? a4v.x : (kk == 1) ? a4v.y : (kk == 2) ? a4v.z : a4v.w;
            o0.x += b0 * wv.x; o0.y += b0 * wv.y; o0.z += b0 * wv.z; o0.w += b0 * wv.w;
            o1.x += b1v * wv.x; o1.y += b1v * wv.y; o1.z += b1v * wv.z; o1.w += b1v * wv.w;
            o2.x += b2v * wv.x; o2.y += b2v * wv.y; o2.z += b2v * wv.z; o2.w += b2v * wv.w;
            o3.x += b3 * wv.x; o3.y += b3 * wv.y; o3.z += b3 * wv.z; o3.w += b3 * wv.w;
            o4.x += b4 * wv.x; o4.y += b4 * wv.y; o4.z += b4 * wv.z; o4.w += b4 * wv.w;
        }
    }
    int rb = blockIdx.x * NPB + r0;
    if (rb + 0 < n) nt_store4(out + (size_t)(rb + 0) * 128 + c4, o0);
    if (rb + 1 < n) nt_store4(out + (size_t)(rb + 1) * 128 + c4, o1);
    if (rb + 2 < n) nt_store4(out + (size_t)(rb + 2) * 128 + c4, o2);
    if (rb + 3 < n) nt_store4(out + (size_t)(rb + 3) * 128 + c4, o3);
    if (rb + 4 < n) nt_store4(out + (size_t)(rb + 4) * 128 + c4, o4);
}

extern "C" void kernel_launch(void* const* d_in, const int* in_sizes, int n_in,
                              void* d_out, int out_size, void* d_ws, size_t ws_size,
                              hipStream_t stream){
    const int*   x    = (const int*)d_in[0];
    const int*   ei   = (const int*)d_in[1];
    const float* emb  = (const float*)d_in[2];
    const float* W1   = (const float*)d_in[3];
    const float* b1   = (const float*)d_in[4];
    const float* W2   = (const float*)d_in[5];
    const float* b2   = (const float*)d_in[6];
    const int N = in_sizes[0];
    const int E = in_sizes[1] / 2;
    const int* srcv = ei;
    const int* dstv = ei + E;
    float* out = (float*)d_out;

    char* p = (char*)d_ws;
    auto alloc = [&](size_t bytes) -> char* {
        char* r = p; p += (bytes + 255) & ~(size_t)255; return r;
    };
    int nb = cdiv(N, 256);
    int*            ecount  = (int*)           alloc((size_t)(N + 8) * 4); // +8: gcur
    int*            gcur    = ecount + N;
    int*            offsets = (int*)           alloc((size_t)N * 4);
    int*            bsum    = (int*)           alloc((size_t)nb * 4);
    float*          dinv    = (float*)         alloc((size_t)N * 4);
    int*            csr     = (int*)           alloc((size_t)E * 4);
    unsigned short* es      = (unsigned short*)alloc((size_t)N * 32 * 2);
    int*            H       = (int*)           alloc((size_t)8 * NC * NPP * 4); // 6.4 MB
    unsigned short* hs      = (unsigned short*)alloc((size_t)N * 128 * 2);
    int4*           bnd4    = (int4*)          alloc((size_t)N * 16);
    int*            staged  = (int*)           alloc((size_t)(E + 8 * 65536) * 4);
    (void)ws_size; (void)n_in; (void)out_size;

    const int npp = cdiv(N, 8);          // nodes per partition (== NPP for N=50000)
    const int C   = E / 8 + 65536;       // staged capacity per partition
    const int CH  = cdiv(C, NC);         // edges per chunk
    const int th1 = cdiv(N, 4), th2 = 2 * th1, th3 = 3 * th1;  // src chunk bounds

    // --- CSR build (no global atomics on hot path) ---
    k_zero_i32<<<1, 64, 0, stream>>>(gcur, 8);
    k_bucket  <<<cdiv(E, 1024), 256, 0, stream>>>(srcv, dstv, E, staged, gcur, npp, C);
    k_hist    <<<8 * NC, 256, 0, stream>>>(staged, gcur, C, CH, npp, H);
    k_nodescan<<<nb, 256, 0, stream>>>(H, npp, N, ecount, dinv, bsum);
    k_scanBC  <<<nb, 256, 0, stream>>>(ecount, N, bsum, nb, offsets);
    k_fill3   <<<8 * NC, 256, 0, stream>>>(staged, gcur, C, CH, npp, H, offsets, csr);
    k_part    <<<cdiv(N, 128), 128, 0, stream>>>(offsets, ecount, csr, bnd4, N, th1, th2, th3);

    // --- layer 1 (fused): scale -> [gather+GEMM] -> hs ---
    k_scale <<<cdiv(N * 32, 256), 256, 0, stream>>>(emb, x, dinv, es, N);
    k_l1    <<<cdiv(N, 8), 256, 0, stream>>>(es, offsets, ecount, csr, dinv, W1, b1, hs, N);

    // --- layer 2 (fused, chunk-major): [gather+GEMM] -> out ---
    k_l2    <<<cdiv(N, NPB), 256, 0, stream>>>(hs, offsets, bnd4, csr, dinv, W2, b2, out, N);
}